// Round 10
// baseline (710.916 us; speedup 1.0000x reference)
//
#include <hip/hip_runtime.h>

// ---------------- types / helpers ----------------
typedef __attribute__((ext_vector_type(8))) short bf16x8;           // MFMA A/B frag (8 bf16)
typedef __attribute__((ext_vector_type(8))) unsigned short ushort8; // 16B vector
typedef __attribute__((ext_vector_type(4))) float f32x4;            // MFMA C/D frag

#define NNODES 50000
#define NEDGES 160000
#define MP     50176   // 392*128 padded rows
#define NB_SCAN 196    // ceil(50000/256)

__device__ __forceinline__ float bf2f(unsigned short u) {
  return __uint_as_float(((unsigned int)u) << 16);
}
__device__ __forceinline__ unsigned short f2bf(float f) {
  unsigned int u = __float_as_uint(f);
  u += 0x7fffu + ((u >> 16) & 1u);   // RNE
  return (unsigned short)(u >> 16);
}
__device__ __forceinline__ void gld16(const void* g, void* l) {
  // async global->LDS, 16B per lane; LDS dest = wave-uniform base + lane*16
  __builtin_amdgcn_global_load_lds((__attribute__((address_space(1))) void*)g,
                                   (__attribute__((address_space(3))) void*)l, 16, 0, 0);
}

// ---------------- CSR build ----------------
__global__ void k_hist(const int* __restrict__ row, int* __restrict__ cnt, int n) {
  int i = blockIdx.x * 256 + threadIdx.x;
  if (i < n) atomicAdd(&cnt[row[i]], 1);
}

__global__ void k_block_reduce(const int* __restrict__ cnt, int* __restrict__ bsum, int n) {
  __shared__ int sd[256];
  int i = blockIdx.x * 256 + threadIdx.x;
  sd[threadIdx.x] = (i < n) ? cnt[i] : 0;
  __syncthreads();
  for (int o = 128; o > 0; o >>= 1) {
    if (threadIdx.x < o) sd[threadIdx.x] += sd[threadIdx.x + o];
    __syncthreads();
  }
  if (threadIdx.x == 0) bsum[blockIdx.x] = sd[0];
}

__global__ void k_scan_bsum(const int* __restrict__ bsum, int* __restrict__ boff, int nb,
                            int* __restrict__ rowptr, int n, int E) {
  __shared__ int sd[256];
  int v = (threadIdx.x < nb) ? bsum[threadIdx.x] : 0;
  sd[threadIdx.x] = v;
  __syncthreads();
  for (int o = 1; o < 256; o <<= 1) {
    int t = (threadIdx.x >= o) ? sd[threadIdx.x - o] : 0;
    __syncthreads();
    sd[threadIdx.x] += t;
    __syncthreads();
  }
  if (threadIdx.x < nb) boff[threadIdx.x] = sd[threadIdx.x] - v;  // exclusive
  if (threadIdx.x == 0) rowptr[n] = E;
}

__global__ void k_block_scan(const int* __restrict__ cnt, const int* __restrict__ boff,
                             int* __restrict__ rowptr, int* __restrict__ cursor, int n) {
  __shared__ int sd[256];
  int i = blockIdx.x * 256 + threadIdx.x;
  int v = (i < n) ? cnt[i] : 0;
  sd[threadIdx.x] = v;
  __syncthreads();
  for (int o = 1; o < 256; o <<= 1) {
    int t = (threadIdx.x >= o) ? sd[threadIdx.x - o] : 0;
    __syncthreads();
    sd[threadIdx.x] += t;
    __syncthreads();
  }
  if (i < n) {
    int r = boff[blockIdx.x] + sd[threadIdx.x] - v;  // exclusive
    rowptr[i] = r;
    cursor[i] = r;   // cursor aliases cnt; each thread reads its cnt before writing
  }
}

__global__ void k_scatter(const int* __restrict__ row, const int* __restrict__ col,
                          const float* __restrict__ val, int* __restrict__ cursor,
                          int* __restrict__ scol, float* __restrict__ sval, int n) {
  int e = blockIdx.x * 256 + threadIdx.x;
  if (e < n) {
    int p = atomicAdd(&cursor[row[e]], 1);
    scol[p] = col[e];
    sval[p] = val[e];
  }
}

// ---------------- packing: all weight transposes + bias sums in ONE dispatch ----------------
__global__ void k_pack_all(const float* __restrict__ W1, const float* __restrict__ p1W,
                           const float* __restrict__ W3, const float* __restrict__ W2,
                           const float* __restrict__ p2W,
                           const float* __restrict__ b1, const float* __restrict__ p1b,
                           const float* __restrict__ b2, const float* __restrict__ p2b,
                           unsigned short* __restrict__ B1t, unsigned short* __restrict__ W3t,
                           unsigned short* __restrict__ B2t,
                           float* __restrict__ bias1, float* __restrict__ bias2) {
  int z = blockIdx.z;
  int tx = threadIdx.x, ty = threadIdx.y;
  if (z == 5) {
    if (blockIdx.x || blockIdx.y) return;
    int t = ty * 32 + tx;
    bias1[t] = b1[t] + p1b[t];
    bias1[t + 256] = b1[t + 256] + p1b[t + 256];
    if (t < 64) bias2[t] = b2[t] + p2b[t];
    return;
  }
  const float* src; unsigned short* dst; int K, srcW, nc, dstOff;
  if (z == 0)      { src = W1;  dst = B1t; K = 1024; srcW = 512; nc = 512; dstOff = 0; }
  else if (z == 1) { src = p1W; dst = B1t; K = 1024; srcW = 512; nc = 512; dstOff = 512; }
  else if (z == 2) { src = W3;  dst = W3t; K = 512;  srcW = 512; nc = 512; dstOff = 0; }
  else if (z == 3) { src = W2;  dst = B2t; K = 512;  srcW = 64;  nc = 64;  dstOff = 0; }
  else             { src = p2W; dst = B2t; K = 512;  srcW = 64;  nc = 64;  dstOff = 64; }
  int k0 = blockIdx.x * 32, n0 = blockIdx.y * 32;
  if (k0 >= K || n0 >= nc) return;
  __shared__ float tile[32][33];
  for (int i = ty; i < 32; i += 8)
    tile[i][tx] = src[(size_t)(k0 + i) * srcW + (n0 + tx)];
  __syncthreads();
  for (int i = ty; i < 32; i += 8)
    dst[(size_t)(dstOff + n0 + i) * K + (k0 + tx)] = f2bf(tile[tx][i]);
}

// ---------------- GEMM1 fused f32-A cast: C[M,N](bf16) = X[M,K](f32) @ Bt[N,K]^T ----------------
// R5's proven 128x256/BK=32/3-buf schedule, A reg-staged at DISTANCE 2 (fix of R7's distance-1):
// two named reg sets (aE/aO); per iter: vmcnt(4) [A(t),B(t) drained, A(t+1),B(t+1) in flight] ->
// ds_write A(t) -> lgkmcnt(0) -> barrier -> issue A(t+2) loads + B(t+2) gld16 -> compute.
// Pad rows load zero; fully-pad tail block's C rows are overwritten by SpMM (harmless).
__global__ __launch_bounds__(512, 4) void k_gemm1f(
    const float* __restrict__ X, const unsigned short* __restrict__ Bt,
    unsigned short* __restrict__ C, int M, int N, int K, int nReal) {
  extern __shared__ char smem[];
  const int NT = N >> 8;
  const int nwg = gridDim.x;
  const int q = nwg >> 3, r = nwg & 7;
  const int xcd = blockIdx.x & 7, local = blockIdx.x >> 3;
  const int swz = (xcd < r ? xcd * (q + 1) : r * (q + 1) + (xcd - r) * q) + local;
  const int mt = swz / NT, nt = swz % NT;

  const int tid = threadIdx.x;
  const int w = tid >> 6, lane = tid & 63;
  const int wr = w >> 2, wc = w & 3;            // 2M x 4N waves; wave tile 64 x 64

  // A reg-staging map: quarter p covers row p*64 + (tid>>3), k-group k4 = tid&7 (4 f32 each)
  const int arow = tid >> 3;                    // 0..63
  const int k4 = tid & 7;
  const int ar0 = mt * 128 + arow;
  const int ar1 = ar0 + 64;
  const bool ok0 = ar0 < nReal, ok1 = ar1 < nReal;
  const float* gx0 = X + (size_t)ar0 * K + k4 * 4;
  const float* gx1 = X + (size_t)ar1 * K + k4 * 4;
  const int arow1 = arow + 64;
  const int ac0 = arow * 64 + (((k4 >> 1) ^ ((arow >> 1) & 3)) << 4) + (k4 & 1) * 8;
  const int ac1 = arow1 * 64 + (((k4 >> 1) ^ ((arow1 >> 1) & 3)) << 4) + (k4 & 1) * 8;

  // B staging (gld16): row = tid>>2, chunk = tid&3 (inverse-swizzled source)
  const int brow = tid >> 2;
  const int bchunk = (tid & 3) ^ ((brow >> 1) & 3);
  const unsigned short* gB = Bt + (size_t)(nt * 256 + brow) * K + bchunk * 8;
  const size_t rs128 = (size_t)128 * K;
  const int wb = w << 10;

  // ds_read bases
  const int l15 = lane & 15;
  const int cpos = ((lane >> 4) ^ ((l15 >> 1) & 3)) << 4;
  const int aOff = (wr * 64 + l15) * 64 + cpos;
  const int bOff = 8192 + (wc * 64 + l15) * 64 + cpos;

  f32x4 acc[4][4] = {};
  const int T = K >> 5;                          // even (K=1024 -> 32)
  float4 aE0, aE1, aO0, aO1;
  const float4 fz = {0.f, 0.f, 0.f, 0.f};

  auto STAGE_B = [&](int t) {
    char* db = smem + (t % 3) * 24576 + wb;
    const unsigned short* b = gB + t * 32;
    gld16(b, db + 8192);
    gld16(b + rs128, db + 16384);
  };
  auto WRITE_A = [&](int buf, const float4& q0, const float4& q1) {
    char* base = smem + buf * 24576;
    uint2 u0, u1;
    u0.x = (unsigned)f2bf(q0.x) | ((unsigned)f2bf(q0.y) << 16);
    u0.y = (unsigned)f2bf(q0.z) | ((unsigned)f2bf(q0.w) << 16);
    u1.x = (unsigned)f2bf(q1.x) | ((unsigned)f2bf(q1.y) << 16);
    u1.y = (unsigned)f2bf(q1.z) | ((unsigned)f2bf(q1.w) << 16);
    *(uint2*)(base + ac0) = u0;
    *(uint2*)(base + ac1) = u1;
  };
  auto COMPUTE = [&](int bb) {
    bf16x8 af[4];
#pragma unroll
    for (int m = 0; m < 4; ++m) af[m] = *(const bf16x8*)(smem + bb + aOff + m * 1024);
    __builtin_amdgcn_s_setprio(1);
#pragma unroll
    for (int n = 0; n < 4; ++n) {
      bf16x8 bfr = *(const bf16x8*)(smem + bb + bOff + n * 1024);
#pragma unroll
      for (int m = 0; m < 4; ++m)
        acc[m][n] = __builtin_amdgcn_mfma_f32_16x16x32_bf16(af[m], bfr, acc[m][n], 0, 0, 0);
    }
    __builtin_amdgcn_s_setprio(0);
  };

  // prologue (issue order A(t) before B(t) keeps vmcnt(4) invariant)
  aE0 = ok0 ? *(const float4*)(gx0) : fz;
  aE1 = ok1 ? *(const float4*)(gx1) : fz;
  STAGE_B(0);
  aO0 = ok0 ? *(const float4*)(gx0 + 32) : fz;
  aO1 = ok1 ? *(const float4*)(gx1 + 32) : fz;
  STAGE_B(1);

  for (int t = 0; t < T; t += 2) {
    // ---- even tile t (E regs)
    asm volatile("s_waitcnt vmcnt(4)" ::: "memory");
    WRITE_A(t % 3, aE0, aE1);
    asm volatile("s_waitcnt lgkmcnt(0)" ::: "memory");
    __builtin_amdgcn_s_barrier();
    __builtin_amdgcn_sched_barrier(0);
    if (t + 2 < T) {
      aE0 = ok0 ? *(const float4*)(gx0 + (t + 2) * 32) : fz;
      aE1 = ok1 ? *(const float4*)(gx1 + (t + 2) * 32) : fz;
      STAGE_B(t + 2);
    }
    COMPUTE((t % 3) * 24576);
    // ---- odd tile t+1 (O regs)
    const int u = t + 1;
    if (u < T - 1) asm volatile("s_waitcnt vmcnt(4)" ::: "memory");
    else           asm volatile("s_waitcnt vmcnt(0)" ::: "memory");
    WRITE_A(u % 3, aO0, aO1);
    asm volatile("s_waitcnt lgkmcnt(0)" ::: "memory");
    __builtin_amdgcn_s_barrier();
    __builtin_amdgcn_sched_barrier(0);
    if (u + 2 < T) {
      aO0 = ok0 ? *(const float4*)(gx0 + (u + 2) * 32) : fz;
      aO1 = ok1 ? *(const float4*)(gx1 + (u + 2) * 32) : fz;
      STAGE_B(u + 2);
    }
    COMPUTE((u % 3) * 24576);
  }

  const int r0 = mt * 128 + wr * 64 + (lane >> 4) * 4;
  const int c0e = nt * 256 + wc * 64 + l15;
#pragma unroll
  for (int m = 0; m < 4; ++m)
#pragma unroll
    for (int n = 0; n < 4; ++n)
#pragma unroll
      for (int j = 0; j < 4; ++j)
        C[(size_t)(r0 + m * 16 + j) * N + (c0e + n * 16)] = f2bf(acc[m][n][j]);
}

// ---------------- GEMM-B (N<=512): 128x128 tile, 256 thr, BK=32, 3 blocks/CU ----------------
// (R8 kernel verbatim — best measured for gc3: ~31us each)
__global__ __launch_bounds__(256, 4) void k_gemm128(
    const unsigned short* __restrict__ A, const unsigned short* __restrict__ Bt,
    unsigned short* __restrict__ C, int M, int N, int K) {
  extern __shared__ char smem[];
  const int NT = N >> 7;
  const int nwg = gridDim.x;
  const int q = nwg >> 3, r = nwg & 7;
  const int xcd = blockIdx.x & 7, local = blockIdx.x >> 3;
  const int swz = (xcd < r ? xcd * (q + 1) : r * (q + 1) + (xcd - r) * q) + local;
  const int mt = swz / NT, nt = swz % NT;

  const int tid = threadIdx.x;
  const int w = tid >> 6, lane = tid & 63;
  const int wr = w >> 1, wc = w & 1;            // 2M x 2N waves; wave tile 64 x 64

  const int srow = tid >> 2;
  const int schunk = (tid & 3) ^ ((srow >> 1) & 3);
  const unsigned short* gA = A + (size_t)(mt * 128 + srow) * K + schunk * 8;
  const unsigned short* gB = Bt + (size_t)(nt * 128 + srow) * K + schunk * 8;
  const size_t rs64 = (size_t)64 * K;
  const int wb = w << 10;

  const int l15 = lane & 15;
  const int cpos = ((lane >> 4) ^ ((l15 >> 1) & 3)) << 4;
  const int aOff = (wr * 64 + l15) * 64 + cpos;
  const int bOff = 8192 + (wc * 64 + l15) * 64 + cpos;

  f32x4 acc[4][4] = {};
  const int T = K >> 5;

  auto STAGE = [&](int t) {
    char* db = smem + (t % 3) * 16384 + wb;
    const unsigned short* a = gA + t * 32;
    const unsigned short* b = gB + t * 32;
    gld16(a, db);
    gld16(a + rs64, db + 4096);
    gld16(b, db + 8192);
    gld16(b + rs64, db + 12288);
  };

  STAGE(0); STAGE(1);

  for (int t = 0; t < T; ++t) {
    if (t < T - 1) asm volatile("s_waitcnt vmcnt(4)" ::: "memory");
    else           asm volatile("s_waitcnt vmcnt(0)" ::: "memory");
    __builtin_amdgcn_s_barrier();
    __builtin_amdgcn_sched_barrier(0);
    if (t + 2 < T) STAGE(t + 2);
    const int bb = (t % 3) * 16384;
    bf16x8 af[4];
#pragma unroll
    for (int m = 0; m < 4; ++m) af[m] = *(const bf16x8*)(smem + bb + aOff + m * 1024);
    __builtin_amdgcn_s_setprio(1);
#pragma unroll
    for (int n = 0; n < 4; ++n) {
      bf16x8 bfr = *(const bf16x8*)(smem + bb + bOff + n * 1024);
#pragma unroll
      for (int m = 0; m < 4; ++m)
        acc[m][n] = __builtin_amdgcn_mfma_f32_16x16x32_bf16(af[m], bfr, acc[m][n], 0, 0, 0);
    }
    __builtin_amdgcn_s_setprio(0);
  }

  const int r0 = mt * 128 + wr * 64 + (lane >> 4) * 4;
  const int c0e = nt * 128 + wc * 64 + l15;
#pragma unroll
  for (int m = 0; m < 4; ++m)
#pragma unroll
    for (int n = 0; n < 4; ++n)
#pragma unroll
      for (int j = 0; j < 4; ++j)
        C[(size_t)(r0 + m * 16 + j) * N + (c0e + n * 16)] = f2bf(acc[m][n][j]);
}

// ---------------- SpMM + epilogue (512 feat): out = relu(sum val*s[col] + bias + res) ----------------
// unroll-4: four independent row-gathers issued before accumulation (dependent-chain MLP)
__global__ __launch_bounds__(256) void k_spmm_ep512(
    const int* __restrict__ rowptr, const int* __restrict__ scol, const float* __restrict__ sval,
    const unsigned short* __restrict__ s, int sStride,
    const unsigned short* __restrict__ res, int resStride,
    const float* __restrict__ bias,
    unsigned short* __restrict__ o, int oStride, int nReal, int nTot) {
  int gw = (blockIdx.x * 256 + threadIdx.x) >> 6;
  int lane = threadIdx.x & 63;
  if (gw >= nTot) return;
  unsigned short* op = o + (size_t)gw * oStride + lane * 8;
  if (gw >= nReal) {  // keep pad rows zero for next GEMM's A reads
    *(ushort8*)op = (ushort8){0,0,0,0,0,0,0,0};
    return;
  }
  float acc[8] = {0.f,0.f,0.f,0.f,0.f,0.f,0.f,0.f};
  int e0 = rowptr[gw], e1 = rowptr[gw + 1];
  int e = e0;
  for (; e + 4 <= e1; e += 4) {
    int c0 = scol[e], c1 = scol[e + 1], c2 = scol[e + 2], c3 = scol[e + 3];
    float v0 = sval[e], v1 = sval[e + 1], v2 = sval[e + 2], v3 = sval[e + 3];
    ushort8 s0 = *(const ushort8*)(s + (size_t)c0 * sStride + lane * 8);
    ushort8 s1 = *(const ushort8*)(s + (size_t)c1 * sStride + lane * 8);
    ushort8 s2 = *(const ushort8*)(s + (size_t)c2 * sStride + lane * 8);
    ushort8 s3 = *(const ushort8*)(s + (size_t)c3 * sStride + lane * 8);
#pragma unroll
    for (int k = 0; k < 8; ++k)
      acc[k] += v0 * bf2f(s0[k]) + v1 * bf2f(s1[k]) + v2 * bf2f(s2[k]) + v3 * bf2f(s3[k]);
  }
  if (e + 2 <= e1) {
    int c0 = scol[e], c1 = scol[e + 1];
    float v0 = sval[e], v1 = sval[e + 1];
    ushort8 s0 = *(const ushort8*)(s + (size_t)c0 * sStride + lane * 8);
    ushort8 s1 = *(const ushort8*)(s + (size_t)c1 * sStride + lane * 8);
#pragma unroll
    for (int k = 0; k < 8; ++k) acc[k] += v0 * bf2f(s0[k]) + v1 * bf2f(s1[k]);
    e += 2;
  }
  if (e < e1) {
    int c = scol[e];
    float v = sval[e];
    ushort8 sv = *(const ushort8*)(s + (size_t)c * sStride + lane * 8);
#pragma unroll
    for (int k = 0; k < 8; ++k) acc[k] += v * bf2f(sv[k]);
  }
  ushort8 rv = *(const ushort8*)(res + (size_t)gw * resStride + lane * 8);
  ushort8 ov;
#pragma unroll
  for (int k = 0; k < 8; ++k) {
    float tt = acc[k] + bias[lane * 8 + k] + bf2f(rv[k]);
    ov[k] = f2bf(fmaxf(tt, 0.f));
  }
  *(ushort8*)op = ov;
}

// ---------------- final: 64-wide SpMM + bias + res + relu + log_softmax ----------------
__global__ __launch_bounds__(256) void k_spmm_lsm(
    const int* __restrict__ rowptr, const int* __restrict__ scol, const float* __restrict__ sval,
    const unsigned short* __restrict__ g2, const float* __restrict__ bias2,
    float* __restrict__ out, int n) {
  int gw = (blockIdx.x * 256 + threadIdx.x) >> 6;
  int lane = threadIdx.x & 63;
  if (gw >= n) return;
  int e0 = rowptr[gw], e1 = rowptr[gw + 1];
  float acc = 0.f;
  int e = e0;
  for (; e + 2 <= e1; e += 2) {
    int c0 = scol[e], c1 = scol[e + 1];
    float v0 = sval[e], v1 = sval[e + 1];
    float a0 = bf2f(g2[(size_t)c0 * 128 + lane]);
    float a1 = bf2f(g2[(size_t)c1 * 128 + lane]);
    acc += v0 * a0 + v1 * a1;
  }
  if (e < e1) acc += sval[e] * bf2f(g2[(size_t)scol[e] * 128 + lane]);
  float t = acc + bias2[lane] + bf2f(g2[(size_t)gw * 128 + 64 + lane]);
  float v = fmaxf(t, 0.f);
  float m = v;
#pragma unroll
  for (int o = 32; o > 0; o >>= 1) m = fmaxf(m, __shfl_xor(m, o));
  float ex = __expf(v - m);
  float ss = ex;
#pragma unroll
  for (int o = 32; o > 0; o >>= 1) ss += __shfl_xor(ss, o);
  out[(size_t)gw * 64 + lane] = v - m - __logf(ss);
}

// ---------------- launch ----------------
extern "C" void kernel_launch(void* const* d_in, const int* in_sizes, int n_in,
                              void* d_out, int out_size, void* d_ws, size_t ws_size,
                              hipStream_t stream) {
  const float* x    = (const float*)d_in[0];
  const int*   arow = (const int*)d_in[1];
  const int*   acol = (const int*)d_in[2];
  const float* aval = (const float*)d_in[3];
  const float* W1   = (const float*)d_in[4];
  const float* b1   = (const float*)d_in[5];
  const float* p1W  = (const float*)d_in[6];
  const float* p1b  = (const float*)d_in[7];
  const float* W3   = (const float*)d_in[8];
  const float* b3   = (const float*)d_in[9];
  const float* W2   = (const float*)d_in[10];
  const float* b2   = (const float*)d_in[11];
  const float* p2W  = (const float*)d_in[12];
  const float* p2b  = (const float*)d_in[13];
  float* out = (float*)d_out;

  char* wsp = (char*)d_ws;
  size_t off = 0;
  auto take = [&](size_t bytes) -> char* {
    char* p = wsp + off;
    off = (off + bytes + 255) & ~(size_t)255;
    return p;
  };
  unsigned short* g1  = (unsigned short*)take((size_t)MP * 1024 * 2);  // gemm1 out [s|res]
  unsigned short* h   = (unsigned short*)take((size_t)MP * 512 * 2);   // hidden state
  unsigned short* B1t = (unsigned short*)take((size_t)1024 * 1024 * 2);
  unsigned short* W3t = (unsigned short*)take((size_t)512 * 512 * 2);
  unsigned short* B2t = (unsigned short*)take((size_t)128 * 512 * 2);
  float* bias1 = (float*)take(512 * 4);
  float* bias2 = (float*)take(64 * 4);
  int*   cnt    = (int*)take((size_t)NNODES * 4);   // reused as cursor
  int*   rowptr = (int*)take((size_t)(NNODES + 1) * 4);
  int*   bsum   = (int*)take(256 * 4);
  int*   boff   = (int*)take(256 * 4);
  int*   scol   = (int*)take((size_t)NEDGES * 4);
  float* sval   = (float*)take((size_t)NEDGES * 4);
  unsigned short* s  = g1;  // alias: g1 dead after layer-1 SpMM (MP*512 fits)
  unsigned short* g2 = g1;  // alias: s dead after last gc3 SpMM

  // CSR build
  hipMemsetAsync(cnt, 0, (size_t)NNODES * 4, stream);
  k_hist<<<(NEDGES + 255) / 256, 256, 0, stream>>>(arow, cnt, NEDGES);
  k_block_reduce<<<NB_SCAN, 256, 0, stream>>>(cnt, bsum, NNODES);
  k_scan_bsum<<<1, 256, 0, stream>>>(bsum, boff, NB_SCAN, rowptr, NNODES, NEDGES);
  k_block_scan<<<NB_SCAN, 256, 0, stream>>>(cnt, boff, rowptr, cnt, NNODES);
  k_scatter<<<(NEDGES + 255) / 256, 256, 0, stream>>>(arow, acol, aval, cnt, scol, sval, NEDGES);

  // pack weights/biases
  k_pack_all<<<dim3(32, 16, 6), dim3(32, 8), 0, stream>>>(W1, p1W, W3, W2, p2W,
                                                          b1, p1b, b2, p2b,
                                                          B1t, W3t, B2t, bias1, bias2);

  // layer 1 (fused f32-A cast, distance-2): g1 = [x@W1 | x@p1W]; h = relu(spmm + b1 + res + p1b)
  k_gemm1f<<<392 * 4, 512, 73728, stream>>>(x, B1t, g1, MP, 1024, 1024, NNODES);
  k_spmm_ep512<<<MP / 4, 256, 0, stream>>>(rowptr, scol, sval, g1, 1024, g1 + 512, 1024,
                                           bias1, h, 512, NNODES, MP);
  // 4 x gc3 (shared W3): s = h@W3 ; h = relu(spmm + b3 + h)
  for (int i = 0; i < 4; ++i) {
    k_gemm128<<<392 * 4, 256, 49152, stream>>>(h, W3t, s, MP, 512, 512);
    k_spmm_ep512<<<MP / 4, 256, 0, stream>>>(rowptr, scol, sval, s, 512, h, 512,
                                             b3, h, 512, NNODES, MP);
  }
  // final: g2 = [h@W2 | h@p2W] ; out = log_softmax(relu(spmm + b2 + res + p2b))
  k_gemm128<<<392, 256, 49152, stream>>>(h, B2t, g2, MP, 128, 512);
  k_spmm_lsm<<<(NNODES + 3) / 4, 256, 0, stream>>>(rowptr, scol, sval, g2, bias2, out, NNODES);
}

// Round 11
// 582.795 us; speedup vs baseline: 1.2198x; 1.2198x over previous
//
#include <hip/hip_runtime.h>

// ---------------- types / helpers ----------------
typedef __attribute__((ext_vector_type(8))) short bf16x8;           // MFMA A/B frag (8 bf16)
typedef __attribute__((ext_vector_type(8))) unsigned short ushort8; // 16B vector
typedef __attribute__((ext_vector_type(4))) float f32x4;            // MFMA C/D frag

#define NNODES 50000
#define NEDGES 160000
#define MP     50176   // 392*128 padded rows
#define NB_SCAN 196    // ceil(50000/256)
#define CAST_SLICES 49 // ceil((MP*1024/8/256)=25088 / 512)

__device__ __forceinline__ float bf2f(unsigned short u) {
  return __uint_as_float(((unsigned int)u) << 16);
}
__device__ __forceinline__ unsigned short f2bf(float f) {
  unsigned int u = __float_as_uint(f);
  u += 0x7fffu + ((u >> 16) & 1u);   // RNE
  return (unsigned short)(u >> 16);
}
__device__ __forceinline__ void gld16(const void* g, void* l) {
  // async global->LDS, 16B per lane; LDS dest = wave-uniform base + lane*16
  __builtin_amdgcn_global_load_lds((__attribute__((address_space(1))) void*)g,
                                   (__attribute__((address_space(3))) void*)l, 16, 0, 0);
}

// ---------------- CSR build ----------------
__global__ void k_hist(const int* __restrict__ row, int* __restrict__ cnt, int n) {
  int i = blockIdx.x * 256 + threadIdx.x;
  if (i < n) atomicAdd(&cnt[row[i]], 1);
}

__global__ void k_block_reduce(const int* __restrict__ cnt, int* __restrict__ bsum, int n) {
  __shared__ int sd[256];
  int i = blockIdx.x * 256 + threadIdx.x;
  sd[threadIdx.x] = (i < n) ? cnt[i] : 0;
  __syncthreads();
  for (int o = 128; o > 0; o >>= 1) {
    if (threadIdx.x < o) sd[threadIdx.x] += sd[threadIdx.x + o];
    __syncthreads();
  }
  if (threadIdx.x == 0) bsum[blockIdx.x] = sd[0];
}

// merged: per-block local scan of bsum (replaces k_scan_bsum dispatch) + element scan
__global__ void k_block_scan(const int* __restrict__ cnt, const int* __restrict__ bsum,
                             int* __restrict__ rowptr, int* __restrict__ cursor, int n, int E) {
  __shared__ int sb[256];
  __shared__ int sd[256];
  int i = blockIdx.x * 256 + threadIdx.x;
  sb[threadIdx.x] = (threadIdx.x < NB_SCAN) ? bsum[threadIdx.x] : 0;
  int v = (i < n) ? cnt[i] : 0;
  sd[threadIdx.x] = v;
  __syncthreads();
  // inclusive scan of bsum (every block does the same tiny scan)
  for (int o = 1; o < 256; o <<= 1) {
    int t = (threadIdx.x >= o) ? sb[threadIdx.x - o] : 0;
    __syncthreads();
    sb[threadIdx.x] += t;
    __syncthreads();
  }
  const int boffv = sb[blockIdx.x] - bsum[blockIdx.x];  // exclusive block offset
  // inclusive scan of this block's counts
  for (int o = 1; o < 256; o <<= 1) {
    int t = (threadIdx.x >= o) ? sd[threadIdx.x - o] : 0;
    __syncthreads();
    sd[threadIdx.x] += t;
    __syncthreads();
  }
  if (i < n) {
    int r = boffv + sd[threadIdx.x] - v;  // exclusive
    rowptr[i] = r;
    cursor[i] = r;   // cursor aliases cnt; each thread reads its cnt before writing
  }
  if (blockIdx.x == 0 && threadIdx.x == 0) rowptr[n] = E;
}

__global__ void k_scatter(const int* __restrict__ row, const int* __restrict__ col,
                          const float* __restrict__ val, int* __restrict__ cursor,
                          int* __restrict__ scol, float* __restrict__ sval, int n) {
  int e = blockIdx.x * 256 + threadIdx.x;
  if (e < n) {
    int p = atomicAdd(&cursor[row[e]], 1);
    scol[p] = col[e];
    sval[p] = val[e];
  }
}

// ---------------- packing: weight transposes + bias sums + x cast in ONE dispatch ----------------
// z = 0..4: weight transpose jobs; z = 5: bias sums; z = 6..54: x -> bf16 cast slices
__global__ void k_pack_all(const float* __restrict__ W1, const float* __restrict__ p1W,
                           const float* __restrict__ W3, const float* __restrict__ W2,
                           const float* __restrict__ p2W,
                           const float* __restrict__ b1, const float* __restrict__ p1b,
                           const float* __restrict__ b2, const float* __restrict__ p2b,
                           const float* __restrict__ x,
                           unsigned short* __restrict__ B1t, unsigned short* __restrict__ W3t,
                           unsigned short* __restrict__ B2t, unsigned short* __restrict__ xb,
                           float* __restrict__ bias1, float* __restrict__ bias2, int nRealRows) {
  int z = blockIdx.z;
  int tx = threadIdx.x, ty = threadIdx.y;
  if (z >= 6) {
    // cast slice: linear block = (z-6)*512 + by*32 + bx, 256 thr, 8 bf16/thr
    int b = (z - 6) * 512 + blockIdx.y * 32 + blockIdx.x;
    size_t idx = ((size_t)b * 256 + (ty * 32 + tx)) * 8;
    if (idx >= (size_t)MP * 1024) return;
    int row = (int)(idx >> 10);
    ushort8 o;
    if (row < nRealRows) {
      float4 a = *(const float4*)(x + idx);
      float4 c = *(const float4*)(x + idx + 4);
      o[0] = f2bf(a.x); o[1] = f2bf(a.y); o[2] = f2bf(a.z); o[3] = f2bf(a.w);
      o[4] = f2bf(c.x); o[5] = f2bf(c.y); o[6] = f2bf(c.z); o[7] = f2bf(c.w);
    } else {
      o = (ushort8){0,0,0,0,0,0,0,0};
    }
    *(ushort8*)(xb + idx) = o;
    return;
  }
  if (z == 5) {
    if (blockIdx.x || blockIdx.y) return;
    int t = ty * 32 + tx;
    bias1[t] = b1[t] + p1b[t];
    bias1[t + 256] = b1[t + 256] + p1b[t + 256];
    if (t < 64) bias2[t] = b2[t] + p2b[t];
    return;
  }
  const float* src; unsigned short* dst; int K, srcW, nc, dstOff;
  if (z == 0)      { src = W1;  dst = B1t; K = 1024; srcW = 512; nc = 512; dstOff = 0; }
  else if (z == 1) { src = p1W; dst = B1t; K = 1024; srcW = 512; nc = 512; dstOff = 512; }
  else if (z == 2) { src = W3;  dst = W3t; K = 512;  srcW = 512; nc = 512; dstOff = 0; }
  else if (z == 3) { src = W2;  dst = B2t; K = 512;  srcW = 64;  nc = 64;  dstOff = 0; }
  else             { src = p2W; dst = B2t; K = 512;  srcW = 64;  nc = 64;  dstOff = 64; }
  int k0 = blockIdx.x * 32, n0 = blockIdx.y * 32;
  if (k0 >= K || n0 >= nc) return;
  __shared__ float tile[32][33];
  for (int i = ty; i < 32; i += 8)
    tile[i][tx] = src[(size_t)(k0 + i) * srcW + (n0 + tx)];
  __syncthreads();
  for (int i = ty; i < 32; i += 8)
    dst[(size_t)(dstOff + n0 + i) * K + (k0 + tx)] = f2bf(tile[tx][i]);
}

// ---------------- GEMM-A (N>=256): 128x256 tile, BK=32, 3 bufs, dist-2 ----------------
// (R5/R9 kernel verbatim — best measured for GEMM1: ~131us, MfmaUtil 35%, 0 conflicts)
__global__ __launch_bounds__(512, 4) void k_gemm128x256(
    const unsigned short* __restrict__ A, const unsigned short* __restrict__ Bt,
    unsigned short* __restrict__ C, int M, int N, int K) {
  extern __shared__ char smem[];
  const int NT = N >> 8;
  const int nwg = gridDim.x;
  const int q = nwg >> 3, r = nwg & 7;
  const int xcd = blockIdx.x & 7, local = blockIdx.x >> 3;
  const int swz = (xcd < r ? xcd * (q + 1) : r * (q + 1) + (xcd - r) * q) + local;
  const int mt = swz / NT, nt = swz % NT;

  const int tid = threadIdx.x;
  const int w = tid >> 6, lane = tid & 63;
  const int wr = w >> 2, wc = w & 3;            // 2M x 4N waves; wave tile 64 x 64

  const int srow = tid >> 2;
  const int schunk = (tid & 3) ^ ((tid >> 3) & 3);
  const unsigned short* gA = A + (size_t)(mt * 128 + srow) * K + schunk * 8;
  const unsigned short* gB = Bt + (size_t)(nt * 256 + srow) * K + schunk * 8;
  const size_t rs128 = (size_t)128 * K;
  const int wb = w << 10;

  const int l15 = lane & 15;
  const int cpos = ((lane >> 4) ^ ((l15 >> 1) & 3)) << 4;
  const int aOff = (wr * 64 + l15) * 64 + cpos;
  const int bOff = 8192 + (wc * 64 + l15) * 64 + cpos;

  f32x4 acc[4][4] = {};
  const int T = K >> 5;

  auto STAGE = [&](int t) {
    char* db = smem + (t % 3) * 24576 + wb;
    const unsigned short* a = gA + t * 32;
    const unsigned short* b = gB + t * 32;
    gld16(a, db);
    gld16(b, db + 8192);
    gld16(b + rs128, db + 16384);
  };

  STAGE(0); STAGE(1);

  for (int t = 0; t < T; ++t) {
    if (t < T - 1) asm volatile("s_waitcnt vmcnt(3)" ::: "memory");
    else           asm volatile("s_waitcnt vmcnt(0)" ::: "memory");
    __builtin_amdgcn_s_barrier();
    __builtin_amdgcn_sched_barrier(0);
    if (t + 2 < T) STAGE(t + 2);
    const int bb = (t % 3) * 24576;
    bf16x8 af[4];
#pragma unroll
    for (int m = 0; m < 4; ++m) af[m] = *(const bf16x8*)(smem + bb + aOff + m * 1024);
    __builtin_amdgcn_s_setprio(1);
#pragma unroll
    for (int n = 0; n < 4; ++n) {
      bf16x8 bfr = *(const bf16x8*)(smem + bb + bOff + n * 1024);
#pragma unroll
      for (int m = 0; m < 4; ++m)
        acc[m][n] = __builtin_amdgcn_mfma_f32_16x16x32_bf16(af[m], bfr, acc[m][n], 0, 0, 0);
    }
    __builtin_amdgcn_s_setprio(0);
  }

  const int r0 = mt * 128 + wr * 64 + (lane >> 4) * 4;
  const int c0e = nt * 256 + wc * 64 + l15;
#pragma unroll
  for (int m = 0; m < 4; ++m)
#pragma unroll
    for (int n = 0; n < 4; ++n)
#pragma unroll
      for (int j = 0; j < 4; ++j)
        C[(size_t)(r0 + m * 16 + j) * N + (c0e + n * 16)] = f2bf(acc[m][n][j]);
}

// ---------------- GEMM-B (N<=512): 128x128 tile, 256 thr, BK=32, 3 blocks/CU ----------------
// (R8/R9 kernel verbatim — best measured for gc3: ~31us each)
__global__ __launch_bounds__(256, 4) void k_gemm128(
    const unsigned short* __restrict__ A, const unsigned short* __restrict__ Bt,
    unsigned short* __restrict__ C, int M, int N, int K) {
  extern __shared__ char smem[];
  const int NT = N >> 7;
  const int nwg = gridDim.x;
  const int q = nwg >> 3, r = nwg & 7;
  const int xcd = blockIdx.x & 7, local = blockIdx.x >> 3;
  const int swz = (xcd < r ? xcd * (q + 1) : r * (q + 1) + (xcd - r) * q) + local;
  const int mt = swz / NT, nt = swz % NT;

  const int tid = threadIdx.x;
  const int w = tid >> 6, lane = tid & 63;
  const int wr = w >> 1, wc = w & 1;            // 2M x 2N waves; wave tile 64 x 64

  const int srow = tid >> 2;
  const int schunk = (tid & 3) ^ ((srow >> 1) & 3);
  const unsigned short* gA = A + (size_t)(mt * 128 + srow) * K + schunk * 8;
  const unsigned short* gB = Bt + (size_t)(nt * 128 + srow) * K + schunk * 8;
  const size_t rs64 = (size_t)64 * K;
  const int wb = w << 10;

  const int l15 = lane & 15;
  const int cpos = ((lane >> 4) ^ ((l15 >> 1) & 3)) << 4;
  const int aOff = (wr * 64 + l15) * 64 + cpos;
  const int bOff = 8192 + (wc * 64 + l15) * 64 + cpos;

  f32x4 acc[4][4] = {};
  const int T = K >> 5;

  auto STAGE = [&](int t) {
    char* db = smem + (t % 3) * 16384 + wb;
    const unsigned short* a = gA + t * 32;
    const unsigned short* b = gB + t * 32;
    gld16(a, db);
    gld16(a + rs64, db + 4096);
    gld16(b, db + 8192);
    gld16(b + rs64, db + 12288);
  };

  STAGE(0); STAGE(1);

  for (int t = 0; t < T; ++t) {
    if (t < T - 1) asm volatile("s_waitcnt vmcnt(4)" ::: "memory");
    else           asm volatile("s_waitcnt vmcnt(0)" ::: "memory");
    __builtin_amdgcn_s_barrier();
    __builtin_amdgcn_sched_barrier(0);
    if (t + 2 < T) STAGE(t + 2);
    const int bb = (t % 3) * 16384;
    bf16x8 af[4];
#pragma unroll
    for (int m = 0; m < 4; ++m) af[m] = *(const bf16x8*)(smem + bb + aOff + m * 1024);
    __builtin_amdgcn_s_setprio(1);
#pragma unroll
    for (int n = 0; n < 4; ++n) {
      bf16x8 bfr = *(const bf16x8*)(smem + bb + bOff + n * 1024);
#pragma unroll
      for (int m = 0; m < 4; ++m)
        acc[m][n] = __builtin_amdgcn_mfma_f32_16x16x32_bf16(af[m], bfr, acc[m][n], 0, 0, 0);
    }
    __builtin_amdgcn_s_setprio(0);
  }

  const int r0 = mt * 128 + wr * 64 + (lane >> 4) * 4;
  const int c0e = nt * 128 + wc * 64 + l15;
#pragma unroll
  for (int m = 0; m < 4; ++m)
#pragma unroll
    for (int n = 0; n < 4; ++n)
#pragma unroll
      for (int j = 0; j < 4; ++j)
        C[(size_t)(r0 + m * 16 + j) * N + (c0e + n * 16)] = f2bf(acc[m][n][j]);
}

// ---------------- SpMM + epilogue (512 feat): out = relu(sum val*s[col] + bias + res) ----------------
// unroll-4: four independent row-gathers issued before accumulation (dependent-chain MLP)
__global__ __launch_bounds__(256) void k_spmm_ep512(
    const int* __restrict__ rowptr, const int* __restrict__ scol, const float* __restrict__ sval,
    const unsigned short* __restrict__ s, int sStride,
    const unsigned short* __restrict__ res, int resStride,
    const float* __restrict__ bias,
    unsigned short* __restrict__ o, int oStride, int nReal, int nTot) {
  int gw = (blockIdx.x * 256 + threadIdx.x) >> 6;
  int lane = threadIdx.x & 63;
  if (gw >= nTot) return;
  unsigned short* op = o + (size_t)gw * oStride + lane * 8;
  if (gw >= nReal) {  // keep pad rows zero for next GEMM's A reads
    *(ushort8*)op = (ushort8){0,0,0,0,0,0,0,0};
    return;
  }
  float acc[8] = {0.f,0.f,0.f,0.f,0.f,0.f,0.f,0.f};
  int e0 = rowptr[gw], e1 = rowptr[gw + 1];
  int e = e0;
  for (; e + 4 <= e1; e += 4) {
    int c0 = scol[e], c1 = scol[e + 1], c2 = scol[e + 2], c3 = scol[e + 3];
    float v0 = sval[e], v1 = sval[e + 1], v2 = sval[e + 2], v3 = sval[e + 3];
    ushort8 s0 = *(const ushort8*)(s + (size_t)c0 * sStride + lane * 8);
    ushort8 s1 = *(const ushort8*)(s + (size_t)c1 * sStride + lane * 8);
    ushort8 s2 = *(const ushort8*)(s + (size_t)c2 * sStride + lane * 8);
    ushort8 s3 = *(const ushort8*)(s + (size_t)c3 * sStride + lane * 8);
#pragma unroll
    for (int k = 0; k < 8; ++k)
      acc[k] += v0 * bf2f(s0[k]) + v1 * bf2f(s1[k]) + v2 * bf2f(s2[k]) + v3 * bf2f(s3[k]);
  }
  if (e + 2 <= e1) {
    int c0 = scol[e], c1 = scol[e + 1];
    float v0 = sval[e], v1 = sval[e + 1];
    ushort8 s0 = *(const ushort8*)(s + (size_t)c0 * sStride + lane * 8);
    ushort8 s1 = *(const ushort8*)(s + (size_t)c1 * sStride + lane * 8);
#pragma unroll
    for (int k = 0; k < 8; ++k) acc[k] += v0 * bf2f(s0[k]) + v1 * bf2f(s1[k]);
    e += 2;
  }
  if (e < e1) {
    int c = scol[e];
    float v = sval[e];
    ushort8 sv = *(const ushort8*)(s + (size_t)c * sStride + lane * 8);
#pragma unroll
    for (int k = 0; k < 8; ++k) acc[k] += v * bf2f(sv[k]);
  }
  ushort8 rv = *(const ushort8*)(res + (size_t)gw * resStride + lane * 8);
  ushort8 ov;
#pragma unroll
  for (int k = 0; k < 8; ++k) {
    float tt = acc[k] + bias[lane * 8 + k] + bf2f(rv[k]);
    ov[k] = f2bf(fmaxf(tt, 0.f));
  }
  *(ushort8*)op = ov;
}

// ---------------- final: 64-wide SpMM + bias + res + relu + log_softmax ----------------
__global__ __launch_bounds__(256) void k_spmm_lsm(
    const int* __restrict__ rowptr, const int* __restrict__ scol, const float* __restrict__ sval,
    const unsigned short* __restrict__ g2, const float* __restrict__ bias2,
    float* __restrict__ out, int n) {
  int gw = (blockIdx.x * 256 + threadIdx.x) >> 6;
  int lane = threadIdx.x & 63;
  if (gw >= n) return;
  int e0 = rowptr[gw], e1 = rowptr[gw + 1];
  float acc = 0.f;
  int e = e0;
  for (; e + 2 <= e1; e += 2) {
    int c0 = scol[e], c1 = scol[e + 1];
    float v0 = sval[e], v1 = sval[e + 1];
    float a0 = bf2f(g2[(size_t)c0 * 128 + lane]);
    float a1 = bf2f(g2[(size_t)c1 * 128 + lane]);
    acc += v0 * a0 + v1 * a1;
  }
  if (e < e1) acc += sval[e] * bf2f(g2[(size_t)scol[e] * 128 + lane]);
  float t = acc + bias2[lane] + bf2f(g2[(size_t)gw * 128 + 64 + lane]);
  float v = fmaxf(t, 0.f);
  float m = v;
#pragma unroll
  for (int o = 32; o > 0; o >>= 1) m = fmaxf(m, __shfl_xor(m, o));
  float ex = __expf(v - m);
  float ss = ex;
#pragma unroll
  for (int o = 32; o > 0; o >>= 1) ss += __shfl_xor(ss, o);
  out[(size_t)gw * 64 + lane] = v - m - __logf(ss);
}

// ---------------- launch ----------------
extern "C" void kernel_launch(void* const* d_in, const int* in_sizes, int n_in,
                              void* d_out, int out_size, void* d_ws, size_t ws_size,
                              hipStream_t stream) {
  const float* x    = (const float*)d_in[0];
  const int*   arow = (const int*)d_in[1];
  const int*   acol = (const int*)d_in[2];
  const float* aval = (const float*)d_in[3];
  const float* W1   = (const float*)d_in[4];
  const float* b1   = (const float*)d_in[5];
  const float* p1W  = (const float*)d_in[6];
  const float* p1b  = (const float*)d_in[7];
  const float* W3   = (const float*)d_in[8];
  const float* b3   = (const float*)d_in[9];
  const float* W2   = (const float*)d_in[10];
  const float* b2   = (const float*)d_in[11];
  const float* p2W  = (const float*)d_in[12];
  const float* p2b  = (const float*)d_in[13];
  float* out = (float*)d_out;

  char* wsp = (char*)d_ws;
  size_t off = 0;
  auto take = [&](size_t bytes) -> char* {
    char* p = wsp + off;
    off = (off + bytes + 255) & ~(size_t)255;
    return p;
  };
  unsigned short* xb  = (unsigned short*)take((size_t)MP * 1024 * 2);
  unsigned short* g1  = (unsigned short*)take((size_t)MP * 1024 * 2);
  unsigned short* B1t = (unsigned short*)take((size_t)1024 * 1024 * 2);
  unsigned short* W3t = (unsigned short*)take((size_t)512 * 512 * 2);
  unsigned short* B2t = (unsigned short*)take((size_t)128 * 512 * 2);
  float* bias1 = (float*)take(512 * 4);
  float* bias2 = (float*)take(64 * 4);
  int*   cnt    = (int*)take((size_t)NNODES * 4);   // reused as cursor
  int*   rowptr = (int*)take((size_t)(NNODES + 1) * 4);
  int*   bsum   = (int*)take(256 * 4);
  int*   scol   = (int*)take((size_t)NEDGES * 4);
  float* sval   = (float*)take((size_t)NEDGES * 4);
  unsigned short* h  = xb;  // alias: xb dead after GEMM1
  unsigned short* s  = g1;  // alias: g1 dead after layer-1 SpMM
  unsigned short* g2 = g1;  // alias: s dead after last gc3 SpMM

  // CSR build (scan_bsum folded into block_scan)
  hipMemsetAsync(cnt, 0, (size_t)NNODES * 4, stream);
  k_hist<<<(NEDGES + 255) / 256, 256, 0, stream>>>(arow, cnt, NEDGES);
  k_block_reduce<<<NB_SCAN, 256, 0, stream>>>(cnt, bsum, NNODES);
  k_block_scan<<<NB_SCAN, 256, 0, stream>>>(cnt, bsum, rowptr, cnt, NNODES, NEDGES);
  k_scatter<<<(NEDGES + 255) / 256, 256, 0, stream>>>(arow, acol, aval, cnt, scol, sval, NEDGES);

  // pack weights/biases + cast x (one dispatch)
  k_pack_all<<<dim3(32, 16, 6 + CAST_SLICES), dim3(32, 8), 0, stream>>>(
      W1, p1W, W3, W2, p2W, b1, p1b, b2, p2b, x,
      B1t, W3t, B2t, xb, bias1, bias2, NNODES);

  // layer 1: g1 = [x@W1 | x@p1W] ; h = relu(spmm + b1 + res + p1b)
  k_gemm128x256<<<392 * 4, 512, 73728, stream>>>(xb, B1t, g1, MP, 1024, 1024);
  k_spmm_ep512<<<MP / 4, 256, 0, stream>>>(rowptr, scol, sval, g1, 1024, g1 + 512, 1024,
                                           bias1, h, 512, NNODES, MP);
  // 4 x gc3 (shared W3): s = h@W3 ; h = relu(spmm + b3 + h)
  for (int i = 0; i < 4; ++i) {
    k_gemm128<<<392 * 4, 256, 49152, stream>>>(h, W3t, s, MP, 512, 512);
    k_spmm_ep512<<<MP / 4, 256, 0, stream>>>(rowptr, scol, sval, s, 512, h, 512,
                                             b3, h, 512, NNODES, MP);
  }
  // final: g2 = [h@W2 | h@p2W] ; out = log_softmax(relu(spmm + b2 + res + p2b))
  k_gemm128<<<392, 256, 49152, stream>>>(h, B2t, g2, MP, 128, 512);
  k_spmm_lsm<<<(NNODES + 3) / 4, 256, 0, stream>>>(rowptr, scol, sval, g2, bias2, out, NNODES);
}